// Round 2
// baseline (144.000 us; speedup 1.0000x reference)
//
#include <hip/hip_runtime.h>
#include <stdint.h>

typedef unsigned short ushort_t;
typedef ushort_t u16x8 __attribute__((ext_vector_type(8)));
typedef __bf16 bf16x8 __attribute__((ext_vector_type(8)));
typedef float f32x4 __attribute__((ext_vector_type(4)));

#define DET 736
#define NPAD 768

#define GPTR(p) ((const __attribute__((address_space(1))) unsigned int*)(p))
#define LPTR(p) ((__attribute__((address_space(3))) unsigned int*)(p))

__device__ __forceinline__ ushort_t f2bf(float f) {
    unsigned u = __builtin_bit_cast(unsigned, f);
    u += 0x7FFFu + ((u >> 16) & 1u);
    return (ushort_t)(u >> 16);
}

// pure fp32 -> bf16 cast, 8 elements/thread (cos weight folded into Bt)
__global__ void cast_x(const float* __restrict__ in, ushort_t* __restrict__ out, int total) {
    int idx = (blockIdx.x * blockDim.x + threadIdx.x) * 8;
    if (idx >= total) return;
    float4 a = *(const float4*)(in + idx);
    float4 b = *(const float4*)(in + idx + 4);
    u16x8 o;
    o[0] = f2bf(a.x); o[1] = f2bf(a.y); o[2] = f2bf(a.z); o[3] = f2bf(a.w);
    o[4] = f2bf(b.x); o[5] = f2bf(b.y); o[6] = f2bf(b.z); o[7] = f2bf(b.w);
    *(u16x8*)(out + idx) = o;
}

// Bt[n][k] = cosw[k] * f[k - n + 735]; rows n>=736 zero.  (W symmetric.)
__global__ void prep_bt(const float* __restrict__ filt, ushort_t* __restrict__ Bt) {
    int idx = blockIdx.x * blockDim.x + threadIdx.x;
    if (idx >= NPAD * DET) return;
    int n = idx / DET;
    int k = idx - n * DET;
    float w = 0.05f * cosf(((float)k - 367.5f) * 0.001f);
    float v = (n < DET) ? w * filt[k - n + (DET - 1)] : 0.0f;  // index in [0,1471) always
    Bt[idx] = f2bf(v);
}

// OUT[M x 736] = X[M x 736] * W'[736 x 736], bf16 MFMA, 128x128 tile, BK=32,
// global_load_lds width-16 staging (m97 rung).
__global__ __launch_bounds__(256) void gemm_bt(
    const ushort_t* __restrict__ A,   // M x DET bf16 bits
    const ushort_t* __restrict__ Bt,  // NPAD x DET bf16 bits
    float* __restrict__ C, int M)
{
    __shared__ ushort_t As[128 * 32];
    __shared__ ushort_t Bs[128 * 32];

    const int tid  = threadIdx.x;
    const int lane = tid & 63;
    const int warp = tid >> 6;   // 0..3
    const int wm   = warp & 1;   // 2x2 wave grid
    const int wn   = warp >> 1;
    const int quad = lane >> 4;  // 0..3
    const int l16  = lane & 15;

    const size_t row_a0 = (size_t)blockIdx.x * 128;
    const size_t row_b0 = (size_t)blockIdx.y * 128;

    // staging: tile = 128 rows x 32 k = 512 x 16B chunks; chunk c -> LDS byte c*16.
    // Wave w, pass p covers chunks p*256 + w*64 + lane => LDS base is wave-uniform,
    // lane-sequential *16B — exactly the global_load_lds deposit pattern.
    const int c0 = warp * 64 + lane;
    const int c1 = c0 + 256;
    const int r0 = c0 >> 2, q0 = c0 & 3;
    const int r1 = c1 >> 2, q1 = c1 & 3;

    const ushort_t* a0p = A  + (row_a0 + r0) * DET + q0 * 8;
    const ushort_t* a1p = A  + (row_a0 + r1) * DET + q1 * 8;
    const ushort_t* b0p = Bt + (row_b0 + r0) * DET + q0 * 8;
    const ushort_t* b1p = Bt + (row_b0 + r1) * DET + q1 * 8;

    f32x4 acc[4][4];
#pragma unroll
    for (int i = 0; i < 4; ++i)
#pragma unroll
        for (int jx = 0; jx < 4; ++jx)
            acc[i][jx] = (f32x4){0.f, 0.f, 0.f, 0.f};

    for (int k0 = 0; k0 < DET; k0 += 32) {
        if (k0) __syncthreads();  // prior iter's ds_reads done before DMA overwrites
        __builtin_amdgcn_global_load_lds(GPTR(a0p + k0), LPTR(As + warp * 512),        16, 0, 0);
        __builtin_amdgcn_global_load_lds(GPTR(a1p + k0), LPTR(As + 2048 + warp * 512), 16, 0, 0);
        __builtin_amdgcn_global_load_lds(GPTR(b0p + k0), LPTR(Bs + warp * 512),        16, 0, 0);
        __builtin_amdgcn_global_load_lds(GPTR(b1p + k0), LPTR(Bs + 2048 + warp * 512), 16, 0, 0);
        __syncthreads();          // drains vmcnt -> tile visible

        u16x8 af[4], bfr[4];
#pragma unroll
        for (int mi = 0; mi < 4; ++mi)
            af[mi] = *(const u16x8*)(As + (wm * 64 + mi * 16 + l16) * 32 + quad * 8);
#pragma unroll
        for (int ni = 0; ni < 4; ++ni)
            bfr[ni] = *(const u16x8*)(Bs + (wn * 64 + ni * 16 + l16) * 32 + quad * 8);
#pragma unroll
        for (int mi = 0; mi < 4; ++mi)
#pragma unroll
            for (int ni = 0; ni < 4; ++ni)
                acc[mi][ni] = __builtin_amdgcn_mfma_f32_16x16x32_bf16(
                    __builtin_bit_cast(bf16x8, af[mi]),
                    __builtin_bit_cast(bf16x8, bfr[ni]),
                    acc[mi][ni], 0, 0, 0);
    }

    // epilogue: C/D layout col=lane&15, row=quad*4+reg [verified mapping]
#pragma unroll
    for (int mi = 0; mi < 4; ++mi) {
#pragma unroll
        for (int ni = 0; ni < 4; ++ni) {
            int colg = (int)row_b0 + wn * 64 + ni * 16 + l16;
            if (colg < DET) {
#pragma unroll
                for (int r = 0; r < 4; ++r) {
                    size_t rowg = row_a0 + wm * 64 + mi * 16 + quad * 4 + r;
                    C[rowg * DET + colg] = acc[mi][ni][r];
                }
            }
        }
    }
}

extern "C" void kernel_launch(void* const* d_in, const int* in_sizes, int n_in,
                              void* d_out, int out_size, void* d_ws, size_t ws_size,
                              hipStream_t stream) {
    const float* sino = (const float*)d_in[0];
    const float* filt = (const float*)d_in[1];
    int total = in_sizes[0];     // 16*1*1152*736 = 13,565,952
    int M = total / DET;         // 18432

    ushort_t* Xbf = (ushort_t*)d_ws;
    ushort_t* Btb = Xbf + (size_t)total;   // 27.1MB offset, 16B-aligned
    float* out = (float*)d_out;

    cast_x<<<(total / 8 + 255) / 256, 256, 0, stream>>>(sino, Xbf, total);
    prep_bt<<<(NPAD * DET + 255) / 256, 256, 0, stream>>>(filt, Btb);

    dim3 grid(M / 128, NPAD / 128);  // 144 x 6
    gemm_bt<<<grid, 256, 0, stream>>>(Xbf, Btb, out, M);
}